// Round 1
// baseline (589.538 us; speedup 1.0000x reference)
//
#include <hip/hip_runtime.h>
#include <hip/hip_bf16.h>
#include <math.h>

#define NN   50000
#define EE   800000
#define INF  512
#define HIDF 256
#define OUTF 64
#define MTILES (NN/16)   // 3125

using short8 = __attribute__((ext_vector_type(8))) short;
using f32x4  = __attribute__((ext_vector_type(4))) float;

static __device__ __forceinline__ short f2bf(float f){
  unsigned u = __builtin_bit_cast(unsigned, f);
  u += 0x7fff + ((u >> 16) & 1);        // round-to-nearest-even
  return (short)(u >> 16);
}

// ---------------- row_ptr: lower_bound over sorted a_row ----------------
__global__ void k_rowptr(const int* __restrict__ a_row, int* __restrict__ row_ptr){
  int i = blockIdx.x * blockDim.x + threadIdx.x;
  if (i > NN) return;
  int lo = 0, hi = EE;
  while (lo < hi){ int mid = (lo + hi) >> 1; if (a_row[mid] < i) lo = mid + 1; else hi = mid; }
  row_ptr[i] = lo;
}

// -------- transpose + fp32->bf16: src [K,Ncols] -> dst [Ncols,K] --------
__global__ void k_transpose_bf16(const float* __restrict__ src, short* __restrict__ dst,
                                 int K, int Ncols){
  int idx = blockIdx.x * blockDim.x + threadIdx.x;
  if (idx >= K * Ncols) return;
  int k = idx / Ncols, n = idx % Ncols;
  dst[n * K + k] = f2bf(src[idx]);
}

// ---------------- GEMM1: C[NN,HIDF] = X[NN,INF] @ W1 ----------------
// one wave computes 16 rows x 256 cols; A converted fp32->bf16 in-register
__global__ __launch_bounds__(256) void k_gemm1(const float* __restrict__ X,
                                               const short* __restrict__ BT, // [HIDF][INF]
                                               float* __restrict__ C){
  int wave = threadIdx.x >> 6, lane = threadIdx.x & 63;
  int tile_m = blockIdx.x * 4 + wave;
  if (tile_m >= MTILES) return;
  int m0 = tile_m * 16, l16 = lane & 15, quad = lane >> 4;

  f32x4 acc[16];
  #pragma unroll
  for (int t = 0; t < 16; t++) acc[t] = (f32x4){0.f,0.f,0.f,0.f};

  const float* arow = X + (size_t)(m0 + l16) * INF + quad * 8;
  for (int kk = 0; kk < INF/32; kk++){
    const float4* ap = (const float4*)(arow + kk * 32);
    float4 a0 = ap[0], a1 = ap[1];
    short8 af;
    af[0]=f2bf(a0.x); af[1]=f2bf(a0.y); af[2]=f2bf(a0.z); af[3]=f2bf(a0.w);
    af[4]=f2bf(a1.x); af[5]=f2bf(a1.y); af[6]=f2bf(a1.z); af[7]=f2bf(a1.w);
    #pragma unroll
    for (int nt = 0; nt < 16; nt++){
      short8 bf = *(const short8*)(BT + (size_t)(nt*16 + l16) * INF + kk*32 + quad*8);
      acc[nt] = __builtin_amdgcn_mfma_f32_16x16x32_bf16(af, bf, acc[nt], 0, 0, 0);
    }
  }
  #pragma unroll
  for (int nt = 0; nt < 16; nt++){
    int col = nt*16 + l16;
    #pragma unroll
    for (int r = 0; r < 4; r++)
      C[(size_t)(m0 + quad*4 + r) * HIDF + col] = acc[nt][r];
  }
}

// ---- SpMM1 + ReLU + dropout -> h (bf16): one block per row, 256 threads ----
__global__ __launch_bounds__(256) void k_spmm1(const int* __restrict__ row_ptr,
                                               const int* __restrict__ a_col,
                                               const float* __restrict__ a_val,
                                               const float* __restrict__ XW1,
                                               const int* __restrict__ drop_mask,
                                               short* __restrict__ hb){
  int r = blockIdx.x, tid = threadIdx.x;
  int s = row_ptr[r], e = row_ptr[r+1];
  float acc = 0.f;
  for (int i = s; i < e; i++){
    float v = a_val[i];
    int   c = a_col[i];
    acc += v * XW1[(size_t)c * HIDF + tid];
  }
  acc = fmaxf(acc, 0.f);
  acc *= (float)drop_mask[(size_t)r * HIDF + tid] * 2.0f;
  hb[(size_t)r * HIDF + tid] = f2bf(acc);
}

// ---------------- GEMM2: C[NN,OUTF] = h[NN,HIDF] @ W2 ----------------
__global__ __launch_bounds__(256) void k_gemm2(const short* __restrict__ A,  // hb [NN][HIDF]
                                               const short* __restrict__ BT, // [OUTF][HIDF]
                                               float* __restrict__ C){
  int wave = threadIdx.x >> 6, lane = threadIdx.x & 63;
  int tile_m = blockIdx.x * 4 + wave;
  if (tile_m >= MTILES) return;
  int m0 = tile_m * 16, l16 = lane & 15, quad = lane >> 4;

  f32x4 acc[4];
  #pragma unroll
  for (int t = 0; t < 4; t++) acc[t] = (f32x4){0.f,0.f,0.f,0.f};

  const short* ar = A + (size_t)(m0 + l16) * HIDF + quad * 8;
  for (int kk = 0; kk < HIDF/32; kk++){
    short8 af = *(const short8*)(ar + kk * 32);
    #pragma unroll
    for (int nt = 0; nt < 4; nt++){
      short8 bf = *(const short8*)(BT + (size_t)(nt*16 + l16) * HIDF + kk*32 + quad*8);
      acc[nt] = __builtin_amdgcn_mfma_f32_16x16x32_bf16(af, bf, acc[nt], 0, 0, 0);
    }
  }
  #pragma unroll
  for (int nt = 0; nt < 4; nt++){
    int col = nt*16 + l16;
    #pragma unroll
    for (int r = 0; r < 4; r++)
      C[(size_t)(m0 + quad*4 + r) * OUTF + col] = acc[nt][r];
  }
}

// -------- SpMM2 + log_softmax: one wave per row, lane = class ----------
__global__ __launch_bounds__(256) void k_spmm2_lsm(const int* __restrict__ row_ptr,
                                                   const int* __restrict__ a_col,
                                                   const float* __restrict__ a_val,
                                                   const float* __restrict__ HW2,
                                                   float* __restrict__ out){
  int wave = threadIdx.x >> 6, lane = threadIdx.x & 63;
  int r = blockIdx.x * 4 + wave;
  int s = row_ptr[r], e = row_ptr[r+1];
  float acc = 0.f;
  for (int i = s; i < e; i++)
    acc += a_val[i] * HW2[(size_t)a_col[i] * OUTF + lane];

  float m = acc;
  #pragma unroll
  for (int o = 32; o > 0; o >>= 1) m = fmaxf(m, __shfl_xor(m, o));
  float ex = expf(acc - m);
  float ssum = ex;
  #pragma unroll
  for (int o = 32; o > 0; o >>= 1) ssum += __shfl_xor(ssum, o);
  out[(size_t)r * OUTF + lane] = acc - m - logf(ssum);
}

extern "C" void kernel_launch(void* const* d_in, const int* in_sizes, int n_in,
                              void* d_out, int out_size, void* d_ws, size_t ws_size,
                              hipStream_t stream) {
  const float* X      = (const float*)d_in[0];
  const float* W1     = (const float*)d_in[1];
  const float* W2     = (const float*)d_in[2];
  const int*   a_row  = (const int*)d_in[3];
  const int*   a_col  = (const int*)d_in[4];
  const float* a_val  = (const float*)d_in[5];
  const int*   drop   = (const int*)d_in[6];
  float*       out    = (float*)d_out;

  char* ws = (char*)d_ws;
  int*   row_ptr = (int*)  (ws);                       // 200,704 B
  short* W1bT    = (short*)(ws + 200704);              // 262,144 B
  short* W2bT    = (short*)(ws + 462848);              //  32,768 B
  float* XW1     = (float*)(ws + 495616);              // 51,200,000 B
  short* hb      = (short*)(ws + 51695616);            // 25,600,000 B
  float* HW2     = (float*)(ws + 77295616);            // 12,800,000 B  (end ~90.1 MB)

  k_rowptr<<<(NN + 1 + 255)/256, 256, 0, stream>>>(a_row, row_ptr);
  k_transpose_bf16<<<(INF*HIDF + 255)/256, 256, 0, stream>>>(W1, W1bT, INF, HIDF);
  k_transpose_bf16<<<(HIDF*OUTF + 255)/256, 256, 0, stream>>>(W2, W2bT, HIDF, OUTF);
  k_gemm1<<<(MTILES + 3)/4, 256, 0, stream>>>(X, W1bT, XW1);
  k_spmm1<<<NN, 256, 0, stream>>>(row_ptr, a_col, a_val, XW1, drop, hb);
  k_gemm2<<<(MTILES + 3)/4, 256, 0, stream>>>(hb, W2bT, HW2);
  k_spmm2_lsm<<<NN/4, 256, 0, stream>>>(row_ptr, a_col, a_val, HW2, out);
}

// Round 2
// 358.290 us; speedup vs baseline: 1.6454x; 1.6454x over previous
//
#include <hip/hip_runtime.h>
#include <hip/hip_bf16.h>
#include <math.h>

#define NN   50000
#define EE   800000
#define INF  512
#define HIDF 256
#define OUTF 64
#define MTILES (NN/16)   // 3125

using short8 = __attribute__((ext_vector_type(8))) short;
using short4v = __attribute__((ext_vector_type(4))) short;
using f32x4  = __attribute__((ext_vector_type(4))) float;

static __device__ __forceinline__ short f2bf(float f){
  unsigned u = __builtin_bit_cast(unsigned, f);
  u += 0x7fff + ((u >> 16) & 1);        // round-to-nearest-even
  return (short)(u >> 16);
}
static __device__ __forceinline__ float bf2f(short s){
  unsigned u = ((unsigned)(unsigned short)s) << 16;
  return __builtin_bit_cast(float, u);
}

// ---------------- row_ptr: lower_bound over sorted a_row ----------------
__global__ void k_rowptr(const int* __restrict__ a_row, int* __restrict__ row_ptr){
  int i = blockIdx.x * blockDim.x + threadIdx.x;
  if (i > NN) return;
  int lo = 0, hi = EE;
  while (lo < hi){ int mid = (lo + hi) >> 1; if (a_row[mid] < i) lo = mid + 1; else hi = mid; }
  row_ptr[i] = lo;
}

// ---- pack W1 [512][256] fp32 -> W1p [16][256][32] bf16 (k-chunked, col-major) ----
__global__ void k_pack_w1(const float* __restrict__ W1, short* __restrict__ W1p){
  int idx = blockIdx.x * blockDim.x + threadIdx.x;   // 512*256
  int k = idx >> 8, col = idx & 255;
  int kk = k >> 5, k2 = k & 31;
  W1p[((kk << 8) + col) * 32 + k2] = f2bf(W1[idx]);
}

// -------- transpose + fp32->bf16: src [K,Ncols] -> dst [Ncols,K] (W2) --------
__global__ void k_transpose_bf16(const float* __restrict__ src, short* __restrict__ dst,
                                 int K, int Ncols){
  int idx = blockIdx.x * blockDim.x + threadIdx.x;
  if (idx >= K * Ncols) return;
  int k = idx / Ncols, n = idx % Ncols;
  dst[n * K + k] = f2bf(src[idx]);
}

// ---------------- GEMM1: XW1b[NN,HIDF](bf16) = X[NN,INF] @ W1 ----------------
// block = 4 waves = 64 rows; B chunk (16 KB source, stride-40 padded in LDS) shared
__global__ __launch_bounds__(256) void k_gemm1(const float* __restrict__ X,
                                               const short* __restrict__ W1p,
                                               short* __restrict__ XW1b){
  __shared__ short lds[256 * 40];   // 20 KB, stride 40 shorts: 2-way conflicts only
  int wave = threadIdx.x >> 6, lane = threadIdx.x & 63;
  int l16 = lane & 15, quad = lane >> 4;
  int m0 = blockIdx.x * 64 + wave * 16;
  int arow_idx = min(m0 + l16, NN - 1);          // clamp: no early return (barriers)
  const float* arow = X + (size_t)arow_idx * INF + quad * 8;

  f32x4 acc[16];
  #pragma unroll
  for (int t = 0; t < 16; t++) acc[t] = (f32x4){0.f,0.f,0.f,0.f};

  for (int kk = 0; kk < INF/32; kk++){
    // cooperative coalesced staging: 16 KB chunk, 4 x 16B per thread
    const short* chunk = W1p + kk * (256*32);
    #pragma unroll
    for (int j = 0; j < 4; j++){
      int off16 = j * 256 + threadIdx.x;          // 16B units
      int col = off16 >> 2, kq = threadIdx.x & 3;
      *(short8*)(lds + col * 40 + kq * 8) = *(const short8*)(chunk + off16 * 8);
    }
    __syncthreads();

    const float4* ap = (const float4*)(arow + kk * 32);
    float4 a0 = ap[0], a1 = ap[1];
    short8 af;
    af[0]=f2bf(a0.x); af[1]=f2bf(a0.y); af[2]=f2bf(a0.z); af[3]=f2bf(a0.w);
    af[4]=f2bf(a1.x); af[5]=f2bf(a1.y); af[6]=f2bf(a1.z); af[7]=f2bf(a1.w);
    #pragma unroll
    for (int nt = 0; nt < 16; nt++){
      short8 bf = *(const short8*)(lds + (nt*16 + l16) * 40 + quad * 8);
      acc[nt] = __builtin_amdgcn_mfma_f32_16x16x32_bf16(af, bf, acc[nt], 0, 0, 0);
    }
    __syncthreads();
  }
  #pragma unroll
  for (int nt = 0; nt < 16; nt++){
    int col = nt*16 + l16;
    #pragma unroll
    for (int r = 0; r < 4; r++){
      int row = m0 + quad*4 + r;
      if (row < NN) XW1b[(size_t)row * HIDF + col] = f2bf(acc[nt][r]);
    }
  }
}

// ---- SpMM1 + ReLU + dropout: one wave per row, 2 edges/iter, 16B gathers ----
__global__ __launch_bounds__(256) void k_spmm1(const int* __restrict__ row_ptr,
                                               const int* __restrict__ a_col,
                                               const float* __restrict__ a_val,
                                               const short* __restrict__ XW1b,
                                               const int* __restrict__ drop_mask,
                                               short* __restrict__ hb){
  int wave = threadIdx.x >> 6, lane = threadIdx.x & 63;
  int r = blockIdx.x * 4 + wave;
  int s = row_ptr[r], e = row_ptr[r+1];
  int g = lane >> 5;          // edge subgroup (2 edges in flight)
  int c8 = lane & 31;         // this lane covers cols c8*8 .. c8*8+7
  float acc[8] = {0,0,0,0,0,0,0,0};

  for (int i = s + g; i < e; i += 2){
    float v = a_val[i];
    int   c = a_col[i];
    short8 x = *(const short8*)(XW1b + (size_t)c * HIDF + c8 * 8);
    #pragma unroll
    for (int j = 0; j < 8; j++) acc[j] += v * bf2f(x[j]);
  }
  #pragma unroll
  for (int j = 0; j < 8; j++) acc[j] += __shfl_xor(acc[j], 32);

  if (lane < 32){
    int4 d0 = *(const int4*)(drop_mask + (size_t)r * HIDF + c8 * 8);
    int4 d1 = *(const int4*)(drop_mask + (size_t)r * HIDF + c8 * 8 + 4);
    short8 o;
    o[0] = f2bf(fmaxf(acc[0],0.f) * (float)d0.x * 2.0f);
    o[1] = f2bf(fmaxf(acc[1],0.f) * (float)d0.y * 2.0f);
    o[2] = f2bf(fmaxf(acc[2],0.f) * (float)d0.z * 2.0f);
    o[3] = f2bf(fmaxf(acc[3],0.f) * (float)d0.w * 2.0f);
    o[4] = f2bf(fmaxf(acc[4],0.f) * (float)d1.x * 2.0f);
    o[5] = f2bf(fmaxf(acc[5],0.f) * (float)d1.y * 2.0f);
    o[6] = f2bf(fmaxf(acc[6],0.f) * (float)d1.z * 2.0f);
    o[7] = f2bf(fmaxf(acc[7],0.f) * (float)d1.w * 2.0f);
    *(short8*)(hb + (size_t)r * HIDF + c8 * 8) = o;
  }
}

// ---------------- GEMM2: HW2b[NN,OUTF](bf16) = h[NN,HIDF] @ W2 ----------------
__global__ __launch_bounds__(256) void k_gemm2(const short* __restrict__ A,  // hb
                                               const short* __restrict__ BT, // [OUTF][HIDF]
                                               short* __restrict__ C){
  int wave = threadIdx.x >> 6, lane = threadIdx.x & 63;
  int tile_m = blockIdx.x * 4 + wave;
  if (tile_m >= MTILES) return;
  int m0 = tile_m * 16, l16 = lane & 15, quad = lane >> 4;

  f32x4 acc[4];
  #pragma unroll
  for (int t = 0; t < 4; t++) acc[t] = (f32x4){0.f,0.f,0.f,0.f};

  const short* ar = A + (size_t)(m0 + l16) * HIDF + quad * 8;
  for (int kk = 0; kk < HIDF/32; kk++){
    short8 af = *(const short8*)(ar + kk * 32);
    #pragma unroll
    for (int nt = 0; nt < 4; nt++){
      short8 bf = *(const short8*)(BT + (size_t)(nt*16 + l16) * HIDF + kk*32 + quad*8);
      acc[nt] = __builtin_amdgcn_mfma_f32_16x16x32_bf16(af, bf, acc[nt], 0, 0, 0);
    }
  }
  #pragma unroll
  for (int nt = 0; nt < 4; nt++){
    int col = nt*16 + l16;
    #pragma unroll
    for (int r = 0; r < 4; r++)
      C[(size_t)(m0 + quad*4 + r) * OUTF + col] = f2bf(acc[nt][r]);
  }
}

// -- SpMM2 + log_softmax: one wave/row, 4 edges/iter, 8B gathers, fused lsm --
__global__ __launch_bounds__(256) void k_spmm2_lsm(const int* __restrict__ row_ptr,
                                                   const int* __restrict__ a_col,
                                                   const float* __restrict__ a_val,
                                                   const short* __restrict__ HW2b,
                                                   float* __restrict__ out){
  int wave = threadIdx.x >> 6, lane = threadIdx.x & 63;
  int r = blockIdx.x * 4 + wave;
  int s = row_ptr[r], e = row_ptr[r+1];
  int g = lane >> 4;          // edge subgroup (4 edges in flight)
  int c4 = lane & 15;         // this lane covers classes c4*4 .. c4*4+3
  float acc[4] = {0,0,0,0};

  for (int i = s + g; i < e; i += 4){
    float v = a_val[i];
    int   c = a_col[i];
    short4v x = *(const short4v*)(HW2b + (size_t)c * OUTF + c4 * 4);
    #pragma unroll
    for (int j = 0; j < 4; j++) acc[j] += v * bf2f(x[j]);
  }
  #pragma unroll
  for (int j = 0; j < 4; j++){
    acc[j] += __shfl_xor(acc[j], 16);
    acc[j] += __shfl_xor(acc[j], 32);
  }
  // log_softmax across 64 classes (all lanes now hold identical per-c4 values)
  float m = fmaxf(fmaxf(acc[0], acc[1]), fmaxf(acc[2], acc[3]));
  #pragma unroll
  for (int o = 1; o <= 8; o <<= 1) m = fmaxf(m, __shfl_xor(m, o));
  float ssum = expf(acc[0]-m) + expf(acc[1]-m) + expf(acc[2]-m) + expf(acc[3]-m);
  #pragma unroll
  for (int o = 1; o <= 8; o <<= 1) ssum += __shfl_xor(ssum, o);
  float ls = logf(ssum);
  if (lane < 16){
    float4 o4 = { acc[0]-m-ls, acc[1]-m-ls, acc[2]-m-ls, acc[3]-m-ls };
    *(float4*)(out + (size_t)r * OUTF + c4 * 4) = o4;
  }
}

extern "C" void kernel_launch(void* const* d_in, const int* in_sizes, int n_in,
                              void* d_out, int out_size, void* d_ws, size_t ws_size,
                              hipStream_t stream) {
  const float* X      = (const float*)d_in[0];
  const float* W1     = (const float*)d_in[1];
  const float* W2     = (const float*)d_in[2];
  const int*   a_row  = (const int*)d_in[3];
  const int*   a_col  = (const int*)d_in[4];
  const float* a_val  = (const float*)d_in[5];
  const int*   drop   = (const int*)d_in[6];
  float*       out    = (float*)d_out;

  char* ws = (char*)d_ws;
  int*   row_ptr = (int*)  (ws);                       //   200,704 B
  short* W1p     = (short*)(ws + 200704);              //   262,144 B
  short* W2bT    = (short*)(ws + 462848);              //    32,768 B
  short* XW1b    = (short*)(ws + 495616);              // 25,600,000 B
  short* hb      = (short*)(ws + 26095616);            // 25,600,000 B
  short* HW2b    = (short*)(ws + 51695616);            //  6,400,000 B (end ~58.1 MB)

  k_rowptr<<<(NN + 1 + 255)/256, 256, 0, stream>>>(a_row, row_ptr);
  k_pack_w1<<<(INF*HIDF)/256, 256, 0, stream>>>(W1, W1p);
  k_transpose_bf16<<<(HIDF*OUTF + 255)/256, 256, 0, stream>>>(W2, W2bT, HIDF, OUTF);
  k_gemm1<<<(NN + 63)/64, 256, 0, stream>>>(X, W1p, XW1b);
  k_spmm1<<<NN/4, 256, 0, stream>>>(row_ptr, a_col, a_val, XW1b, drop, hb);
  k_gemm2<<<(MTILES + 3)/4, 256, 0, stream>>>(hb, W2bT, HW2b);
  k_spmm2_lsm<<<NN/4, 256, 0, stream>>>(row_ptr, a_col, a_val, HW2b, out);
}

// Round 3
// 336.732 us; speedup vs baseline: 1.7508x; 1.0640x over previous
//
#include <hip/hip_runtime.h>
#include <hip/hip_bf16.h>
#include <math.h>

#define NN   50000
#define EE   800000
#define INF  512
#define HIDF 256
#define OUTF 64
#define MTILES (NN/16)   // 3125

using short8 = __attribute__((ext_vector_type(8))) short;
using short4v = __attribute__((ext_vector_type(4))) short;
using f32x4  = __attribute__((ext_vector_type(4))) float;

static __device__ __forceinline__ short f2bf(float f){
  unsigned u = __builtin_bit_cast(unsigned, f);
  u += 0x7fff + ((u >> 16) & 1);        // round-to-nearest-even
  return (short)(u >> 16);
}
static __device__ __forceinline__ float bf2f(short s){
  unsigned u = ((unsigned)(unsigned short)s) << 16;
  return __builtin_bit_cast(float, u);
}

// ---- fused prep: row_ptr (blocks 0..195) | W1 pack (196..707) | W2^T (708..771) ----
__global__ void k_prep(const int* __restrict__ a_row, int* __restrict__ row_ptr,
                       const float* __restrict__ W1, short* __restrict__ W1p,
                       const float* __restrict__ W2, short* __restrict__ W2bT){
  int b = blockIdx.x, tid = threadIdx.x;
  if (b < 196){
    int i = b * 256 + tid;
    if (i > NN) return;
    int lo = 0, hi = EE;
    while (lo < hi){ int mid = (lo + hi) >> 1; if (a_row[mid] < i) lo = mid + 1; else hi = mid; }
    row_ptr[i] = lo;
  } else if (b < 708){
    int idx = (b - 196) * 256 + tid;        // 512*256 elements
    int k = idx >> 8, col = idx & 255;
    int kk = k >> 5, k2 = k & 31;
    W1p[((kk << 8) + col) * 32 + k2] = f2bf(W1[idx]);
  } else {
    int idx = (b - 708) * 256 + tid;        // 256*64 elements
    int k = idx >> 6, n = idx & 63;
    W2bT[n * HIDF + k] = f2bf(W2[idx]);
  }
}

// ---------------- GEMM1: XW1b[NN,HIDF](bf16) = X[NN,INF] @ W1 ----------------
// block = 4 waves = 128 rows; each wave 32 rows x 256 cols: two A-frags share
// every B-frag ds_read (halves LDS pipe pressure vs 16-row waves)
__global__ __launch_bounds__(256) void k_gemm1(const float* __restrict__ X,
                                               const short* __restrict__ W1p,
                                               short* __restrict__ XW1b){
  __shared__ short lds[256 * 40];   // 20 KB, stride 40 shorts: 2-way conflicts only
  int wave = threadIdx.x >> 6, lane = threadIdx.x & 63;
  int l16 = lane & 15, quad = lane >> 4;
  int m0 = blockIdx.x * 128 + wave * 32;
  int r0 = min(m0 + l16, NN - 1);             // clamp: no early return (barriers)
  int r1 = min(m0 + 16 + l16, NN - 1);
  const float* arow0 = X + (size_t)r0 * INF + quad * 8;
  const float* arow1 = X + (size_t)r1 * INF + quad * 8;

  f32x4 acc0[16], acc1[16];
  #pragma unroll
  for (int t = 0; t < 16; t++){ acc0[t] = (f32x4){0.f,0.f,0.f,0.f}; acc1[t] = (f32x4){0.f,0.f,0.f,0.f}; }

  for (int kk = 0; kk < INF/32; kk++){
    // issue A loads early (independent of LDS)
    const float4* ap0 = (const float4*)(arow0 + kk * 32);
    const float4* ap1 = (const float4*)(arow1 + kk * 32);
    float4 a00 = ap0[0], a01 = ap0[1];
    float4 a10 = ap1[0], a11 = ap1[1];

    // cooperative coalesced staging: 16 KB chunk, 4 x 16B per thread
    const short* chunk = W1p + kk * (256*32);
    #pragma unroll
    for (int j = 0; j < 4; j++){
      int off16 = j * 256 + threadIdx.x;          // 16B units
      int col = off16 >> 2, kq = threadIdx.x & 3;
      *(short8*)(lds + col * 40 + kq * 8) = *(const short8*)(chunk + off16 * 8);
    }
    __syncthreads();

    short8 af0, af1;
    af0[0]=f2bf(a00.x); af0[1]=f2bf(a00.y); af0[2]=f2bf(a00.z); af0[3]=f2bf(a00.w);
    af0[4]=f2bf(a01.x); af0[5]=f2bf(a01.y); af0[6]=f2bf(a01.z); af0[7]=f2bf(a01.w);
    af1[0]=f2bf(a10.x); af1[1]=f2bf(a10.y); af1[2]=f2bf(a10.z); af1[3]=f2bf(a10.w);
    af1[4]=f2bf(a11.x); af1[5]=f2bf(a11.y); af1[6]=f2bf(a11.z); af1[7]=f2bf(a11.w);
    #pragma unroll
    for (int nt = 0; nt < 16; nt++){
      short8 bf = *(const short8*)(lds + (nt*16 + l16) * 40 + quad * 8);
      acc0[nt] = __builtin_amdgcn_mfma_f32_16x16x32_bf16(af0, bf, acc0[nt], 0, 0, 0);
      acc1[nt] = __builtin_amdgcn_mfma_f32_16x16x32_bf16(af1, bf, acc1[nt], 0, 0, 0);
    }
    __syncthreads();
  }
  #pragma unroll
  for (int nt = 0; nt < 16; nt++){
    int col = nt*16 + l16;
    #pragma unroll
    for (int r = 0; r < 4; r++){
      int row0 = m0 + quad*4 + r;
      int row1 = m0 + 16 + quad*4 + r;
      if (row0 < NN) XW1b[(size_t)row0 * HIDF + col] = f2bf(acc0[nt][r]);
      if (row1 < NN) XW1b[(size_t)row1 * HIDF + col] = f2bf(acc1[nt][r]);
    }
  }
}

// ---- SpMM1 + ReLU + dropout: one wave/row, 4 edge-groups x 16 lanes x 32B,
// ---- unroll x2 -> 4 independent gathers in flight per lane ----
__global__ __launch_bounds__(256) void k_spmm1(const int* __restrict__ row_ptr,
                                               const int* __restrict__ a_col,
                                               const float* __restrict__ a_val,
                                               const short* __restrict__ XW1b,
                                               const int* __restrict__ drop_mask,
                                               short* __restrict__ hb){
  int wave = threadIdx.x >> 6, lane = threadIdx.x & 63;
  int r = blockIdx.x * 4 + wave;
  int s = row_ptr[r], e = row_ptr[r+1];
  int g = lane >> 4;          // edge subgroup: 4 edges in flight
  int c16 = lane & 15;        // this lane covers cols c16*16 .. +15
  float acc[16];
  #pragma unroll
  for (int j = 0; j < 16; j++) acc[j] = 0.f;

  int i = s + g;
  for (; i + 4 < e; i += 8){
    float v0 = a_val[i];     int c0 = a_col[i];
    float v1 = a_val[i+4];   int c1 = a_col[i+4];
    const short* p0 = XW1b + (size_t)c0 * HIDF + c16 * 16;
    const short* p1 = XW1b + (size_t)c1 * HIDF + c16 * 16;
    short8 x0a = *(const short8*)(p0);
    short8 x0b = *(const short8*)(p0 + 8);
    short8 x1a = *(const short8*)(p1);
    short8 x1b = *(const short8*)(p1 + 8);
    #pragma unroll
    for (int j = 0; j < 8; j++){
      acc[j]   += v0 * bf2f(x0a[j]);  acc[j+8] += v0 * bf2f(x0b[j]);
      acc[j]   += v1 * bf2f(x1a[j]);  acc[j+8] += v1 * bf2f(x1b[j]);
    }
  }
  for (; i < e; i += 4){
    float v = a_val[i];  int c = a_col[i];
    const short* p = XW1b + (size_t)c * HIDF + c16 * 16;
    short8 xa = *(const short8*)(p);
    short8 xb = *(const short8*)(p + 8);
    #pragma unroll
    for (int j = 0; j < 8; j++){
      acc[j] += v * bf2f(xa[j]);  acc[j+8] += v * bf2f(xb[j]);
    }
  }
  #pragma unroll
  for (int j = 0; j < 16; j++){
    acc[j] += __shfl_xor(acc[j], 16);
    acc[j] += __shfl_xor(acc[j], 32);
  }
  if (lane < 16){
    const int* dm = drop_mask + (size_t)r * HIDF + c16 * 16;
    short8 o0, o1;
    #pragma unroll
    for (int j = 0; j < 8; j++){
      o0[j] = f2bf(fmaxf(acc[j],   0.f) * (float)dm[j]   * 2.0f);
      o1[j] = f2bf(fmaxf(acc[j+8], 0.f) * (float)dm[j+8] * 2.0f);
    }
    short* hp = hb + (size_t)r * HIDF + c16 * 16;
    *(short8*)(hp)     = o0;
    *(short8*)(hp + 8) = o1;
  }
}

// ---------------- GEMM2: HW2b[NN,OUTF](bf16) = h[NN,HIDF] @ W2 ----------------
__global__ __launch_bounds__(256) void k_gemm2(const short* __restrict__ A,  // hb
                                               const short* __restrict__ BT, // [OUTF][HIDF]
                                               short* __restrict__ C){
  int wave = threadIdx.x >> 6, lane = threadIdx.x & 63;
  int tile_m = blockIdx.x * 4 + wave;
  if (tile_m >= MTILES) return;
  int m0 = tile_m * 16, l16 = lane & 15, quad = lane >> 4;

  f32x4 acc[4];
  #pragma unroll
  for (int t = 0; t < 4; t++) acc[t] = (f32x4){0.f,0.f,0.f,0.f};

  const short* ar = A + (size_t)(m0 + l16) * HIDF + quad * 8;
  for (int kk = 0; kk < HIDF/32; kk++){
    short8 af = *(const short8*)(ar + kk * 32);
    #pragma unroll
    for (int nt = 0; nt < 4; nt++){
      short8 bf = *(const short8*)(BT + (size_t)(nt*16 + l16) * HIDF + kk*32 + quad*8);
      acc[nt] = __builtin_amdgcn_mfma_f32_16x16x32_bf16(af, bf, acc[nt], 0, 0, 0);
    }
  }
  #pragma unroll
  for (int nt = 0; nt < 4; nt++){
    int col = nt*16 + l16;
    #pragma unroll
    for (int r = 0; r < 4; r++)
      C[(size_t)(m0 + quad*4 + r) * OUTF + col] = f2bf(acc[nt][r]);
  }
}

// -- SpMM2 + log_softmax: one wave/row, 4 edge-groups x 16 lanes x 8B, unroll x2 --
__global__ __launch_bounds__(256) void k_spmm2_lsm(const int* __restrict__ row_ptr,
                                                   const int* __restrict__ a_col,
                                                   const float* __restrict__ a_val,
                                                   const short* __restrict__ HW2b,
                                                   float* __restrict__ out){
  int wave = threadIdx.x >> 6, lane = threadIdx.x & 63;
  int r = blockIdx.x * 4 + wave;
  int s = row_ptr[r], e = row_ptr[r+1];
  int g = lane >> 4;          // edge subgroup (4 edges in flight)
  int c4 = lane & 15;         // this lane covers classes c4*4 .. c4*4+3
  float acc[4] = {0,0,0,0};

  int i = s + g;
  for (; i + 4 < e; i += 8){
    float v0 = a_val[i];    int c0 = a_col[i];
    float v1 = a_val[i+4];  int c1 = a_col[i+4];
    short4v x0 = *(const short4v*)(HW2b + (size_t)c0 * OUTF + c4 * 4);
    short4v x1 = *(const short4v*)(HW2b + (size_t)c1 * OUTF + c4 * 4);
    #pragma unroll
    for (int j = 0; j < 4; j++){ acc[j] += v0 * bf2f(x0[j]); acc[j] += v1 * bf2f(x1[j]); }
  }
  for (; i < e; i += 4){
    float v = a_val[i];  int c = a_col[i];
    short4v x = *(const short4v*)(HW2b + (size_t)c * OUTF + c4 * 4);
    #pragma unroll
    for (int j = 0; j < 4; j++) acc[j] += v * bf2f(x[j]);
  }
  #pragma unroll
  for (int j = 0; j < 4; j++){
    acc[j] += __shfl_xor(acc[j], 16);
    acc[j] += __shfl_xor(acc[j], 32);
  }
  // log_softmax across 64 classes (all lanes now hold identical per-c4 values)
  float m = fmaxf(fmaxf(acc[0], acc[1]), fmaxf(acc[2], acc[3]));
  #pragma unroll
  for (int o = 1; o <= 8; o <<= 1) m = fmaxf(m, __shfl_xor(m, o));
  float ssum = expf(acc[0]-m) + expf(acc[1]-m) + expf(acc[2]-m) + expf(acc[3]-m);
  #pragma unroll
  for (int o = 1; o <= 8; o <<= 1) ssum += __shfl_xor(ssum, o);
  float ls = logf(ssum);
  if (lane < 16){
    float4 o4 = { acc[0]-m-ls, acc[1]-m-ls, acc[2]-m-ls, acc[3]-m-ls };
    *(float4*)(out + (size_t)r * OUTF + c4 * 4) = o4;
  }
}

extern "C" void kernel_launch(void* const* d_in, const int* in_sizes, int n_in,
                              void* d_out, int out_size, void* d_ws, size_t ws_size,
                              hipStream_t stream) {
  const float* X      = (const float*)d_in[0];
  const float* W1     = (const float*)d_in[1];
  const float* W2     = (const float*)d_in[2];
  const int*   a_row  = (const int*)d_in[3];
  const int*   a_col  = (const int*)d_in[4];
  const float* a_val  = (const float*)d_in[5];
  const int*   drop   = (const int*)d_in[6];
  float*       out    = (float*)d_out;

  char* ws = (char*)d_ws;
  int*   row_ptr = (int*)  (ws);                       //   200,704 B
  short* W1p     = (short*)(ws + 200704);              //   262,144 B
  short* W2bT    = (short*)(ws + 462848);              //    32,768 B
  short* XW1b    = (short*)(ws + 495616);              // 25,600,000 B
  short* hb      = (short*)(ws + 26095616);            // 25,600,000 B
  short* HW2b    = (short*)(ws + 51695616);            //  6,400,000 B (end ~58.1 MB)

  k_prep<<<772, 256, 0, stream>>>(a_row, row_ptr, W1, W1p, W2, W2bT);
  k_gemm1<<<(NN + 127)/128, 256, 0, stream>>>(X, W1p, XW1b);
  k_spmm1<<<NN/4, 256, 0, stream>>>(row_ptr, a_col, a_val, XW1b, drop, hb);
  k_gemm2<<<(MTILES + 3)/4, 256, 0, stream>>>(hb, W2bT, HW2b);
  k_spmm2_lsm<<<NN/4, 256, 0, stream>>>(row_ptr, a_col, a_val, HW2b, out);
}